// Round 7
// baseline (106.609 us; speedup 1.0000x reference)
//
#include <hip/hip_runtime.h>
#include <hip/hip_bf16.h>

#define NN 16384
#define DD 512
#define CC 256
#define CAP 192

typedef short bf16x8 __attribute__((ext_vector_type(8)));
typedef short bf16x4 __attribute__((ext_vector_type(4)));
typedef float f32x4 __attribute__((ext_vector_type(4)));

__device__ __forceinline__ short f2bf(float x) {
  __hip_bfloat16 h = __float2bfloat16(x);
  return __builtin_bit_cast(short, h);
}

__global__ void k_zero(int* __restrict__ cur, float* __restrict__ out) {
  cur[threadIdx.x] = 0;
  if (threadIdx.x == 0) *out = 0.f;
}

// 32768 rows -> per-(tensor,class) index lists. grid 128 x 256.
__global__ void k_bucket(const int* __restrict__ lab_s, const int* __restrict__ lab_t,
                         int* __restrict__ cur, int* __restrict__ idx) {
  const int i = blockIdx.x * 256 + threadIdx.x;
  const int t = i >> 14, r = i & 16383;
  const int c = (t ? lab_t : lab_s)[r];
  const int tc = t * 256 + c;
  const int pos = atomicAdd(&cur[tc], 1);
  if (pos < CAP) idx[tc * CAP + pos] = r;
}

// grid 512 (one block per (tensor,class)), 256 threads, f32x4 16B/lane.
// Threads 0-127 (h=0) take even list slots, 128-255 (h=1) odd; LDS combine.
__global__ void k_gather(const float* __restrict__ src, const float* __restrict__ trg,
                         const int* __restrict__ cur, const int* __restrict__ idx,
                         float* __restrict__ sum_s, float* __restrict__ sum_t,
                         float* __restrict__ cnt_s, float* __restrict__ cnt_t) {
  const int tc = blockIdx.x;
  const int t = tc >> 8, c = tc & 255;
  const float* feat = t ? trg : src;
  float* sum = t ? sum_t : sum_s;
  float* cnt = t ? cnt_t : cnt_s;
  const int tid = threadIdx.x;
  const int q = tid & 127, h = tid >> 7;
  const int count = min(cur[tc], CAP);

  __shared__ int lidx[CAP];
  __shared__ f32x4 sh[128];
  if (tid < count) lidx[tid] = idx[tc * CAP + tid];
  __syncthreads();

  f32x4 a = (f32x4){0.f, 0.f, 0.f, 0.f};
  f32x4 b = (f32x4){0.f, 0.f, 0.f, 0.f};
  int r = h;
  for (; r + 2 < count; r += 4) {
    a += *reinterpret_cast<const f32x4*>(feat + (size_t)lidx[r] * DD + q * 4);
    b += *reinterpret_cast<const f32x4*>(feat + (size_t)lidx[r + 2] * DD + q * 4);
  }
  if (r < count)
    a += *reinterpret_cast<const f32x4*>(feat + (size_t)lidx[r] * DD + q * 4);
  a += b;
  if (h == 1) sh[q] = a;
  __syncthreads();
  if (h == 0) {
    a += sh[q];
    *reinterpret_cast<f32x4*>(sum + c * DD + q * 4) = a;
    if (tid == 0) cnt[c] = (float)count;
  }
}

// grid = 256 (class), 256 threads.
// Writes the 3 prototype matrices in PACKED MFMA B-fragment order:
// per mat (131072 u16): elem = kc*8192 + tile*512 + (lhi*16+llo)*8 + j
//   where kc=k>>5, lhi=(k>>3)&3, j=k&7, tile=c>>4, llo=c&15.
__global__ void k_u(const float* __restrict__ sum_s, const float* __restrict__ sum_t,
                    const float* __restrict__ cnt_s, const float* __restrict__ cnt_t,
                    unsigned short* __restrict__ Upk) {
  const int c = blockIdx.x, tid = threadIdx.x;
  const float cs = cnt_s[c], ct = cnt_t[c];
  const float rs = 1.f / cs, rt = 1.f / ct, rst = 1.f / (cs + ct);
  const int tile = c >> 4, llo = c & 15;
#pragma unroll
  for (int kk = 0; kk < 2; ++kk) {
    const int k = tid + kk * 256;
    const float ss = sum_s[c * DD + k], st = sum_t[c * DD + k];
    const int kc = k >> 5, lhi = (k >> 3) & 3, j = k & 7;
    const int e = kc * 8192 + tile * 512 + (lhi * 16 + llo) * 8 + j;
    Upk[0 * 131072 + e] = (unsigned short)f2bf(ss * rs);
    Upk[1 * 131072 + e] = (unsigned short)f2bf(st * rt);
    Upk[2 * 131072 + e] = (unsigned short)f2bf((ss + st) * rst);
  }
}

// grid = 512 blocks, 512 threads (8 waves: wr=w>>2 row-group of 32 rows,
// cw=w&3 col-group of 64 cols per mat). Block: 64 rows x 768 cols.
// Single-buffered B (48KB) + dbuf A -> LDS 62KB -> 2 blocks/CU co-resident;
// classic 2-phase with __syncthreads; cross-block overlap hides the drain.
__global__ __launch_bounds__(512) void k_main(
    const float* __restrict__ src, const float* __restrict__ trg,
    const unsigned short* __restrict__ Upk, float* __restrict__ out) {
  __shared__ short Bs[24576];      // 48 KB: 48 units of 1KB per chunk
  __shared__ short As[2][2048];    // 2 x 4 KB: 4 rowtiles x 512 shorts (frag order)
  __shared__ float smax[3][4][64];
  __shared__ float ssum[3][4][64];
  __shared__ float bred[8];

  const int tid = threadIdx.x;
  const int w = tid >> 6, lane = tid & 63;
  const int lhi = lane >> 4, llo = lane & 15;
  const int wr = w >> 2, cw = w & 3;
  const int row0 = blockIdx.x * 64;
  const float* feat = (row0 < NN) ? src + (size_t)row0 * DD
                                  : trg + (size_t)(row0 - NN) * DD;

  // A staging role: thread -> (row 0..63, k-quad 0..7)
  const int ar = tid >> 3, aq = tid & 7;
  const float* aglob = feat + (size_t)ar * DD + aq * 4;
  const int awoff = (ar >> 4) * 512 + ((aq >> 1) * 16 + (ar & 15)) * 8 + (aq & 1) * 4;

  f32x4 acc[3][2][4];
#pragma unroll
  for (int m = 0; m < 3; ++m)
#pragma unroll
    for (int rt = 0; rt < 2; ++rt)
#pragma unroll
      for (int ct = 0; ct < 4; ++ct)
        acc[m][rt][ct] = (f32x4){0.f, 0.f, 0.f, 0.f};

  auto stageB = [&](int kc) {
#pragma unroll
    for (int s = 0; s < 6; ++s) {
      const int u = s * 8 + w;
      const unsigned short* g =
          Upk + (size_t)(u >> 4) * 131072 + kc * 8192 + (u & 15) * 512 + lane * 8;
      __builtin_amdgcn_global_load_lds(
          (const __attribute__((address_space(1))) unsigned int*)g,
          (__attribute__((address_space(3))) unsigned int*)&Bs[u * 512], 16, 0, 0);
    }
  };
  auto writeA = [&](const float4& v, int buf) {
    bf16x4 b;
    b[0] = f2bf(v.x); b[1] = f2bf(v.y); b[2] = f2bf(v.z); b[3] = f2bf(v.w);
    *reinterpret_cast<bf16x4*>(&As[buf][awoff]) = b;
  };
  auto compute = [&](int abuf) {
    bf16x8 afr[2];
#pragma unroll
    for (int rt = 0; rt < 2; ++rt)
      afr[rt] = *reinterpret_cast<const bf16x8*>(
          &As[abuf][(wr * 2 + rt) * 512 + (lhi * 16 + llo) * 8]);
#pragma unroll
    for (int m = 0; m < 3; ++m)
#pragma unroll
      for (int ct = 0; ct < 4; ++ct) {
        const bf16x8 b = *reinterpret_cast<const bf16x8*>(
            &Bs[(m * 16 + cw * 4 + ct) * 512 + lane * 8]);
#pragma unroll
        for (int rt = 0; rt < 2; ++rt)
          acc[m][rt][ct] =
              __builtin_amdgcn_mfma_f32_16x16x32_bf16(afr[rt], b, acc[m][rt][ct], 0, 0, 0);
      }
  };

  // ---- prologue: stage chunk 0 (B into Bs, A into As[0]); preload A(1) ----
  float4 af = *reinterpret_cast<const float4*>(aglob);   // A(0)
  stageB(0);
  writeA(af, 0);
  af = *reinterpret_cast<const float4*>(aglob + 32);     // A(1)
  __syncthreads();   // drains vmcnt(0)+lgkmcnt(0): chunk 0 staged

#pragma unroll 1
  for (int kc = 0; kc < 16; ++kc) {
    compute(kc & 1);
    __syncthreads();                 // all waves done reading Bs
    if (kc < 15) {
      stageB(kc + 1);
      writeA(af, (kc + 1) & 1);      // af = A(kc+1)
      if (kc < 14)
        af = *reinterpret_cast<const float4*>(aglob + (kc + 2) * 32);
      __syncthreads();               // chunk kc+1 staged (full drain)
    }
  }

  // ---- epilogue: per-row logsumexp over 768 cols (C/D: col=llo, row=4*lhi+q) ----
  float lse[3][2][4];

#pragma unroll
  for (int m = 0; m < 3; ++m)
#pragma unroll
    for (int rt = 0; rt < 2; ++rt)
#pragma unroll
      for (int q = 0; q < 4; ++q) {
        float v = fmaxf(fmaxf(acc[m][rt][0][q], acc[m][rt][1][q]),
                        fmaxf(acc[m][rt][2][q], acc[m][rt][3][q]));
#pragma unroll
        for (int off = 1; off < 16; off <<= 1)
          v = fmaxf(v, __shfl_xor(v, off));
        if (llo == 0) smax[m][cw][wr * 32 + rt * 16 + lhi * 4 + q] = v;
      }
  __syncthreads();
#pragma unroll
  for (int m = 0; m < 3; ++m)
#pragma unroll
    for (int rt = 0; rt < 2; ++rt)
#pragma unroll
      for (int q = 0; q < 4; ++q) {
        const int r = wr * 32 + rt * 16 + lhi * 4 + q;
        lse[m][rt][q] = fmaxf(fmaxf(smax[m][0][r], smax[m][1][r]),
                              fmaxf(smax[m][2][r], smax[m][3][r]));
      }
#pragma unroll
  for (int m = 0; m < 3; ++m)
#pragma unroll
    for (int rt = 0; rt < 2; ++rt)
#pragma unroll
      for (int q = 0; q < 4; ++q) {
        float s = 0.f;
#pragma unroll
        for (int ct = 0; ct < 4; ++ct)
          s += __expf(acc[m][rt][ct][q] - lse[m][rt][q]);
#pragma unroll
        for (int off = 1; off < 16; off <<= 1)
          s += __shfl_xor(s, off);
        if (llo == 0) ssum[m][cw][wr * 32 + rt * 16 + lhi * 4 + q] = s;
      }
  __syncthreads();
#pragma unroll
  for (int m = 0; m < 3; ++m)
#pragma unroll
    for (int rt = 0; rt < 2; ++rt)
#pragma unroll
      for (int q = 0; q < 4; ++q) {
        const int r = wr * 32 + rt * 16 + lhi * 4 + q;
        const float S = ssum[m][0][r] + ssum[m][1][r] + ssum[m][2][r] + ssum[m][3][r];
        lse[m][rt][q] += __logf(S);
      }

  // fused symmetric-KL: sum of e^a(2a-b-c) + e^b(2b-a-c) + e^c(2c-a-b)
  float ks = 0.f;
#pragma unroll
  for (int rt = 0; rt < 2; ++rt)
#pragma unroll
    for (int ct = 0; ct < 4; ++ct)
#pragma unroll
      for (int q = 0; q < 4; ++q) {
        const float a = acc[0][rt][ct][q] - lse[0][rt][q];
        const float b = acc[1][rt][ct][q] - lse[1][rt][q];
        const float c = acc[2][rt][ct][q] - lse[2][rt][q];
        ks += __expf(a) * (2.f * a - b - c) + __expf(b) * (2.f * b - a - c) +
              __expf(c) * (2.f * c - a - b);
      }
#pragma unroll
  for (int off = 1; off < 64; off <<= 1)
    ks += __shfl_xor(ks, off);
  if (lane == 0) bred[w] = ks;
  __syncthreads();
  if (tid == 0) {
    float s = 0.f;
#pragma unroll
    for (int i = 0; i < 8; ++i) s += bred[i];
    atomicAdd(out, s * (1.f / 50331648.f));  // 1/(6 * 2N * C)
  }
}

extern "C" void kernel_launch(void* const* d_in, const int* in_sizes, int n_in,
                              void* d_out, int out_size, void* d_ws, size_t ws_size,
                              hipStream_t stream) {
  const float* src = (const float*)d_in[0];
  const float* trg = (const float*)d_in[1];
  const int* lab_s = (const int*)d_in[2];
  const int* lab_t = (const int*)d_in[3];
  float* out = (float*)d_out;

  float* sum_s = (float*)d_ws;                  // [256*512]
  float* sum_t = sum_s + CC * DD;               // [256*512]
  float* cnt_s = sum_t + CC * DD;               // [256]
  float* cnt_t = cnt_s + CC;                    // [256]
  int* cur = (int*)(cnt_t + CC);                // [512]
  int* idx = cur + 512;                         // [512*CAP]
  unsigned short* Upk = (unsigned short*)(idx + 512 * CAP);  // 3 x [131072] bf16

  k_zero<<<1, 512, 0, stream>>>(cur, out);
  k_bucket<<<128, 256, 0, stream>>>(lab_s, lab_t, cur, idx);
  k_gather<<<512, 256, 0, stream>>>(src, trg, cur, idx, sum_s, sum_t, cnt_s, cnt_t);
  k_u<<<CC, 256, 0, stream>>>(sum_s, sum_t, cnt_s, cnt_t, Upk);
  k_main<<<512, 512, 0, stream>>>(src, trg, Upk, out);
}

// Round 8
// 101.677 us; speedup vs baseline: 1.0485x; 1.0485x over previous
//
#include <hip/hip_runtime.h>
#include <hip/hip_bf16.h>

#define NN 16384
#define DD 512
#define CC 256
#define CAP 192

typedef short bf16x8 __attribute__((ext_vector_type(8)));
typedef short bf16x4 __attribute__((ext_vector_type(4)));
typedef float f32x4 __attribute__((ext_vector_type(4)));

__device__ __forceinline__ short f2bf(float x) {
  __hip_bfloat16 h = __float2bfloat16(x);
  return __builtin_bit_cast(short, h);
}

__global__ void k_zero(int* __restrict__ cur, float* __restrict__ out) {
  cur[threadIdx.x] = 0;
  if (threadIdx.x == 0) *out = 0.f;
}

// 32768 rows -> per-(tensor,class) index lists. grid 128 x 256.
__global__ void k_bucket(const int* __restrict__ lab_s, const int* __restrict__ lab_t,
                         int* __restrict__ cur, int* __restrict__ idx) {
  const int i = blockIdx.x * 256 + threadIdx.x;
  const int t = i >> 14, r = i & 16383;
  const int c = (t ? lab_t : lab_s)[r];
  const int tc = t * 256 + c;
  const int pos = atomicAdd(&cur[tc], 1);
  if (pos < CAP) idx[tc * CAP + pos] = r;
}

// grid 512 (one block per (tensor,class)), 256 threads, f32x4 16B/lane.
__global__ void k_gather(const float* __restrict__ src, const float* __restrict__ trg,
                         const int* __restrict__ cur, const int* __restrict__ idx,
                         float* __restrict__ sum_s, float* __restrict__ sum_t,
                         float* __restrict__ cnt_s, float* __restrict__ cnt_t) {
  const int tc = blockIdx.x;
  const int t = tc >> 8, c = tc & 255;
  const float* feat = t ? trg : src;
  float* sum = t ? sum_t : sum_s;
  float* cnt = t ? cnt_t : cnt_s;
  const int tid = threadIdx.x;
  const int q = tid & 127, h = tid >> 7;
  const int count = min(cur[tc], CAP);

  __shared__ int lidx[CAP];
  __shared__ f32x4 sh[128];
  if (tid < count) lidx[tid] = idx[tc * CAP + tid];
  __syncthreads();

  f32x4 a = (f32x4){0.f, 0.f, 0.f, 0.f};
  f32x4 b = (f32x4){0.f, 0.f, 0.f, 0.f};
  int r = h;
  for (; r + 2 < count; r += 4) {
    a += *reinterpret_cast<const f32x4*>(feat + (size_t)lidx[r] * DD + q * 4);
    b += *reinterpret_cast<const f32x4*>(feat + (size_t)lidx[r + 2] * DD + q * 4);
  }
  if (r < count)
    a += *reinterpret_cast<const f32x4*>(feat + (size_t)lidx[r] * DD + q * 4);
  a += b;
  if (h == 1) sh[q] = a;
  __syncthreads();
  if (h == 0) {
    a += sh[q];
    *reinterpret_cast<f32x4*>(sum + c * DD + q * 4) = a;
    if (tid == 0) cnt[c] = (float)count;
  }
}

// grid = 256 (class), 256 threads.
// Writes the 3 prototype matrices in PACKED MFMA B-fragment order:
// per mat (131072 u16): elem = kc*8192 + tile*512 + (lhi*16+llo)*8 + j
//   where kc=k>>5, lhi=(k>>3)&3, j=k&7, tile=c>>4, llo=c&15.
__global__ void k_u(const float* __restrict__ sum_s, const float* __restrict__ sum_t,
                    const float* __restrict__ cnt_s, const float* __restrict__ cnt_t,
                    unsigned short* __restrict__ Upk) {
  const int c = blockIdx.x, tid = threadIdx.x;
  const float cs = cnt_s[c], ct = cnt_t[c];
  const float rs = 1.f / cs, rt = 1.f / ct, rst = 1.f / (cs + ct);
  const int tile = c >> 4, llo = c & 15;
#pragma unroll
  for (int kk = 0; kk < 2; ++kk) {
    const int k = tid + kk * 256;
    const float ss = sum_s[c * DD + k], st = sum_t[c * DD + k];
    const int kc = k >> 5, lhi = (k >> 3) & 3, j = k & 7;
    const int e = kc * 8192 + tile * 512 + (lhi * 16 + llo) * 8 + j;
    Upk[0 * 131072 + e] = (unsigned short)f2bf(ss * rs);
    Upk[1 * 131072 + e] = (unsigned short)f2bf(st * rt);
    Upk[2 * 131072 + e] = (unsigned short)f2bf((ss + st) * rst);
  }
}

// grid = 512 blocks, 512 threads (8 waves: wr=w>>2 row-group of 32 rows,
// cw=w&3 col-group of 64 cols per mat). Block: 64 rows x 768 cols.
// B loaded DIRECTLY global->VGPR from packed Upk (L2-resident, coalesced 1KB
// units), register ping-pong 1 chunk ahead. A through small dbuf LDS. One raw
// s_barrier + lgkmcnt(0) per chunk; NO vmcnt drain anywhere in the loop.
__global__ __launch_bounds__(512, 1) void k_main(
    const float* __restrict__ src, const float* __restrict__ trg,
    const unsigned short* __restrict__ Upk, float* __restrict__ out) {
  __shared__ short As[2][2048];    // 2 x 4 KB: 4 rowtiles x 512 shorts (frag order)
  __shared__ float smax[3][4][64];
  __shared__ float ssum[3][4][64];
  __shared__ float bred[8];

  const int tid = threadIdx.x;
  const int w = tid >> 6, lane = tid & 63;
  const int lhi = lane >> 4, llo = lane & 15;
  const int wr = w >> 2, cw = w & 3;
  const int row0 = blockIdx.x * 64;
  const float* feat = (row0 < NN) ? src + (size_t)row0 * DD
                                  : trg + (size_t)(row0 - NN) * DD;

  // A staging role: thread -> (row 0..63, k-quad 0..7)
  const int ar = tid >> 3, aq = tid & 7;
  const float* aglob = feat + (size_t)ar * DD + aq * 4;
  const int awoff = (ar >> 4) * 512 + ((aq >> 1) * 16 + (ar & 15)) * 8 + (aq & 1) * 4;
  const unsigned short* bbase = Upk + (cw * 4) * 512 + lane * 8;

  f32x4 acc[3][2][4];
#pragma unroll
  for (int m = 0; m < 3; ++m)
#pragma unroll
    for (int rt = 0; rt < 2; ++rt)
#pragma unroll
      for (int ct = 0; ct < 4; ++ct)
        acc[m][rt][ct] = (f32x4){0.f, 0.f, 0.f, 0.f};

  auto LB = [&](bf16x8 (&B)[12], int kc) {
#pragma unroll
    for (int m = 0; m < 3; ++m)
#pragma unroll
      for (int ct = 0; ct < 4; ++ct)
        B[m * 4 + ct] = *reinterpret_cast<const bf16x8*>(
            bbase + m * 131072 + kc * 8192 + ct * 512);
  };
  auto writeA = [&](const float4& v, int buf) {
    bf16x4 b;
    b[0] = f2bf(v.x); b[1] = f2bf(v.y); b[2] = f2bf(v.z); b[3] = f2bf(v.w);
    *reinterpret_cast<bf16x4*>(&As[buf][awoff]) = b;
  };
  auto FMA = [&](const short* Ab, bf16x8 (&B)[12]) {
    bf16x8 afr[2];
#pragma unroll
    for (int rt = 0; rt < 2; ++rt)
      afr[rt] = *reinterpret_cast<const bf16x8*>(Ab + (wr * 2 + rt) * 512 + lane * 8);
#pragma unroll
    for (int m = 0; m < 3; ++m)
#pragma unroll
      for (int ct = 0; ct < 4; ++ct)
#pragma unroll
        for (int rt = 0; rt < 2; ++rt)
          acc[m][rt][ct] = __builtin_amdgcn_mfma_f32_16x16x32_bf16(
              afr[rt], B[m * 4 + ct], acc[m][rt][ct], 0, 0, 0);
  };

  bf16x8 BX[12], BY[12];

  // ---- prologue: A(0)->As[0]; B(0)->BX; A(1) in flight; B(1)->BY ----
  float4 af = *reinterpret_cast<const float4*>(aglob);       // A(0)
  asm volatile("" ::: "memory");
  LB(BX, 0);
  writeA(af, 0);
  af = *reinterpret_cast<const float4*>(aglob + 32);         // A(1)
  asm volatile("" ::: "memory");
  LB(BY, 1);
  asm volatile("s_waitcnt lgkmcnt(0)" ::: "memory");
  __builtin_amdgcn_s_barrier();

#pragma unroll 1
  for (int it = 0; it < 7; ++it) {
    const int kc = 2 * it;
    // chunk kc: As[0] ready, BX = B(kc); stage A(kc+1), prefetch B(kc+2)
    writeA(af, 1);
    af = *reinterpret_cast<const float4*>(aglob + (kc + 2) * 32);
    FMA(As[0], BX);
    LB(BX, kc + 2);
    asm volatile("s_waitcnt lgkmcnt(0)" ::: "memory");
    __builtin_amdgcn_s_barrier();
    // chunk kc+1: As[1] ready, BY = B(kc+1); stage A(kc+2), prefetch B(kc+3)
    writeA(af, 0);
    af = *reinterpret_cast<const float4*>(aglob + (kc + 3) * 32);
    FMA(As[1], BY);
    LB(BY, kc + 3);
    asm volatile("s_waitcnt lgkmcnt(0)" ::: "memory");
    __builtin_amdgcn_s_barrier();
  }
  // tail: As[0]=A(14), af=A(15), BX=B(14), BY=B(15)
  writeA(af, 1);
  FMA(As[0], BX);          // chunk 14
  asm volatile("s_waitcnt lgkmcnt(0)" ::: "memory");
  __builtin_amdgcn_s_barrier();
  FMA(As[1], BY);          // chunk 15

  // ---- epilogue: per-row logsumexp over 768 cols (C/D: col=llo, row=4*lhi+q) ----
  float lse[3][2][4];

#pragma unroll
  for (int m = 0; m < 3; ++m)
#pragma unroll
    for (int rt = 0; rt < 2; ++rt)
#pragma unroll
      for (int q = 0; q < 4; ++q) {
        float v = fmaxf(fmaxf(acc[m][rt][0][q], acc[m][rt][1][q]),
                        fmaxf(acc[m][rt][2][q], acc[m][rt][3][q]));
#pragma unroll
        for (int off = 1; off < 16; off <<= 1)
          v = fmaxf(v, __shfl_xor(v, off));
        if (llo == 0) smax[m][cw][wr * 32 + rt * 16 + lhi * 4 + q] = v;
      }
  __syncthreads();
#pragma unroll
  for (int m = 0; m < 3; ++m)
#pragma unroll
    for (int rt = 0; rt < 2; ++rt)
#pragma unroll
      for (int q = 0; q < 4; ++q) {
        const int r = wr * 32 + rt * 16 + lhi * 4 + q;
        lse[m][rt][q] = fmaxf(fmaxf(smax[m][0][r], smax[m][1][r]),
                              fmaxf(smax[m][2][r], smax[m][3][r]));
      }
#pragma unroll
  for (int m = 0; m < 3; ++m)
#pragma unroll
    for (int rt = 0; rt < 2; ++rt)
#pragma unroll
      for (int q = 0; q < 4; ++q) {
        float s = 0.f;
#pragma unroll
        for (int ct = 0; ct < 4; ++ct)
          s += __expf(acc[m][rt][ct][q] - lse[m][rt][q]);
#pragma unroll
        for (int off = 1; off < 16; off <<= 1)
          s += __shfl_xor(s, off);
        if (llo == 0) ssum[m][cw][wr * 32 + rt * 16 + lhi * 4 + q] = s;
      }
  __syncthreads();
#pragma unroll
  for (int m = 0; m < 3; ++m)
#pragma unroll
    for (int rt = 0; rt < 2; ++rt)
#pragma unroll
      for (int q = 0; q < 4; ++q) {
        const int r = wr * 32 + rt * 16 + lhi * 4 + q;
        const float S = ssum[m][0][r] + ssum[m][1][r] + ssum[m][2][r] + ssum[m][3][r];
        lse[m][rt][q] += __logf(S);
      }

  // fused symmetric-KL: sum of e^a(2a-b-c) + e^b(2b-a-c) + e^c(2c-a-b)
  float ks = 0.f;
#pragma unroll
  for (int rt = 0; rt < 2; ++rt)
#pragma unroll
    for (int ct = 0; ct < 4; ++ct)
#pragma unroll
      for (int q = 0; q < 4; ++q) {
        const float a = acc[0][rt][ct][q] - lse[0][rt][q];
        const float b = acc[1][rt][ct][q] - lse[1][rt][q];
        const float c = acc[2][rt][ct][q] - lse[2][rt][q];
        ks += __expf(a) * (2.f * a - b - c) + __expf(b) * (2.f * b - a - c) +
              __expf(c) * (2.f * c - a - b);
      }
#pragma unroll
  for (int off = 1; off < 64; off <<= 1)
    ks += __shfl_xor(ks, off);
  if (lane == 0) bred[w] = ks;
  __syncthreads();
  if (tid == 0) {
    float s = 0.f;
#pragma unroll
    for (int i = 0; i < 8; ++i) s += bred[i];
    atomicAdd(out, s * (1.f / 50331648.f));  // 1/(6 * 2N * C)
  }
}

extern "C" void kernel_launch(void* const* d_in, const int* in_sizes, int n_in,
                              void* d_out, int out_size, void* d_ws, size_t ws_size,
                              hipStream_t stream) {
  const float* src = (const float*)d_in[0];
  const float* trg = (const float*)d_in[1];
  const int* lab_s = (const int*)d_in[2];
  const int* lab_t = (const int*)d_in[3];
  float* out = (float*)d_out;

  float* sum_s = (float*)d_ws;                  // [256*512]
  float* sum_t = sum_s + CC * DD;               // [256*512]
  float* cnt_s = sum_t + CC * DD;               // [256]
  float* cnt_t = cnt_s + CC;                    // [256]
  int* cur = (int*)(cnt_t + CC);                // [512]
  int* idx = cur + 512;                         // [512*CAP]
  unsigned short* Upk = (unsigned short*)(idx + 512 * CAP);  // 3 x [131072] bf16

  k_zero<<<1, 512, 0, stream>>>(cur, out);
  k_bucket<<<128, 256, 0, stream>>>(lab_s, lab_t, cur, idx);
  k_gather<<<512, 256, 0, stream>>>(src, trg, cur, idx, sum_s, sum_t, cnt_s, cnt_t);
  k_u<<<CC, 256, 0, stream>>>(sum_s, sum_t, cnt_s, cnt_t, Upk);
  k_main<<<512, 512, 0, stream>>>(src, trg, Upk, out);
}